// Round 1
// baseline (453.504 us; speedup 1.0000x reference)
//
#include <hip/hip_runtime.h>
#include <math.h>

#define N_POS 8192
#define BATCH 4
#define N_GT 512
#define BG (BATCH * N_GT)        // 2048 flattened (b,g) columns
#define EPSV 1e-6f

// workspace layout (floats)
#define WS_PART_MAX 0            // [2048] block partial maxes from k1
#define WS_SC 2048               // [0]=maxdist [1]=pmin [2]=prange [3..6]=n_est[b]
#define WS_S 2064                // [2048] sum_n 1/(w+eps) per (b,g)
#define WS_T1 4112               // [4] sum_n p*minD per batch
#define K1_BLOCKS 2048

__global__ __launch_bounds__(256) void whd_k1_max(const float4* __restrict__ dis,
                                                  float* __restrict__ part) {
    int t = threadIdx.x;
    long gid = (long)blockIdx.x * blockDim.x + t;
    long stride = (long)gridDim.x * blockDim.x;
    long n4 = ((long)N_POS * N_POS) / 4;
    float m = -INFINITY;
    for (long i = gid; i < n4; i += stride) {
        float4 v = dis[i];
        m = fmaxf(m, fmaxf(fmaxf(v.x, v.y), fmaxf(v.z, v.w)));
    }
    #pragma unroll
    for (int off = 32; off; off >>= 1) m = fmaxf(m, __shfl_down(m, off, 64));
    __shared__ float sm[4];
    if ((t & 63) == 0) sm[t >> 6] = m;
    __syncthreads();
    if (t == 0) {
        float mm = fmaxf(fmaxf(sm[0], sm[1]), fmaxf(sm[2], sm[3]));
        part[blockIdx.x] = mm;
    }
}

__global__ __launch_bounds__(1024) void whd_k2_scalars(const float* __restrict__ prob,
                                                       float* __restrict__ wsf) {
    __shared__ float red[1024];
    int t = threadIdx.x;
    // reduce k1 partial maxes
    float m = -INFINITY;
    for (int i = t; i < K1_BLOCKS; i += 1024) m = fmaxf(m, wsf[WS_PART_MAX + i]);
    red[t] = m; __syncthreads();
    for (int s = 512; s; s >>= 1) { if (t < s) red[t] = fmaxf(red[t], red[t + s]); __syncthreads(); }
    float maxdist = red[0]; __syncthreads();
    // min/max of prob_map
    float lmin = INFINITY, lmax = -INFINITY;
    for (int i = t; i < BATCH * N_POS; i += 1024) {
        float v = prob[i];
        lmin = fminf(lmin, v); lmax = fmaxf(lmax, v);
    }
    red[t] = lmin; __syncthreads();
    for (int s = 512; s; s >>= 1) { if (t < s) red[t] = fminf(red[t], red[t + s]); __syncthreads(); }
    float pmin = red[0]; __syncthreads();
    red[t] = lmax; __syncthreads();
    for (int s = 512; s; s >>= 1) { if (t < s) red[t] = fmaxf(red[t], red[t + s]); __syncthreads(); }
    float pmax = red[0]; __syncthreads();
    float prange = pmax - pmin;
    float inv = 1.0f / prange;
    // n_est per batch (sum of clipped-normalized prob)
    for (int b = 0; b < BATCH; b++) {
        float s = 0.f;
        for (int i = t; i < N_POS; i += 1024) {
            float p = (prob[b * N_POS + i] - pmin) * inv;
            p = fminf(fmaxf(p, 0.f), 1.f);
            s += p;
        }
        red[t] = s; __syncthreads();
        for (int st = 512; st; st >>= 1) { if (t < st) red[t] += red[t + st]; __syncthreads(); }
        if (t == 0) wsf[WS_SC + 3 + b] = red[0];
        __syncthreads();
    }
    if (t == 0) {
        wsf[WS_SC + 0] = maxdist;
        wsf[WS_SC + 1] = pmin;
        wsf[WS_SC + 2] = prange;
    }
    // zero accumulators (ws is poisoned 0xAA before every call)
    for (int i = t; i < BG; i += 1024) wsf[WS_S + i] = 0.f;
    if (t < BATCH) wsf[WS_T1 + t] = 0.f;
}

#define ROWS_PER_BLOCK 16
__global__ __launch_bounds__(256) void whd_k3_main(const float* __restrict__ dis,
                                                   const float* __restrict__ prob,
                                                   const int* __restrict__ gt,
                                                   float* __restrict__ wsf) {
    __shared__ float rowbuf[N_POS];     // 32 KB
    __shared__ int gtl[BG];             // 8 KB
    __shared__ float minsh[4][4];       // [wave][batch]
    int t = threadIdx.x;
    int wv = t >> 6, lane = t & 63;
    int row0 = blockIdx.x * ROWS_PER_BLOCK;
    for (int i = t; i < BG; i += 256) gtl[i] = gt[i];
    float maxd = wsf[WS_SC + 0];
    float pmin = wsf[WS_SC + 1];
    float invr = 1.0f / wsf[WS_SC + 2];
    __syncthreads();
    // thread t owns columns t + 256k, k=0..7; batch of column = k>>1
    int c[8];
    #pragma unroll
    for (int k = 0; k < 8; k++) c[k] = gtl[t + 256 * k];
    float acc[8];
    #pragma unroll
    for (int k = 0; k < 8; k++) acc[k] = 0.f;
    float t1sum = 0.f;

    for (int r = 0; r < ROWS_PER_BLOCK; r++) {
        int n = row0 + r;
        __syncthreads();  // protect rowbuf/minsh from previous-iteration readers
        const float4* src = (const float4*)(dis + (size_t)n * N_POS);
        float4* dstl = (float4*)rowbuf;
        for (int i = t; i < N_POS / 4; i += 256) dstl[i] = src[i];
        float pb[4];
        #pragma unroll
        for (int b = 0; b < BATCH; b++) {
            float p = (prob[b * N_POS + n] - pmin) * invr;
            pb[b] = fminf(fmaxf(p, 0.f), 1.f);
        }
        __syncthreads();
        float vmin[4];
        #pragma unroll
        for (int k = 0; k < 8; k++) {
            float v = rowbuf[c[k]];
            int b = k >> 1;
            float w = fmaf(pb[b], v - maxd, maxd) + EPSV;  // (1-p)*M + p*v + eps
            acc[k] += 1.0f / w;
            if ((k & 1) == 0) vmin[b] = v; else vmin[b] = fminf(vmin[b], v);
        }
        #pragma unroll
        for (int b = 0; b < BATCH; b++) {
            float m = vmin[b];
            #pragma unroll
            for (int off = 32; off; off >>= 1) m = fminf(m, __shfl_xor(m, off, 64));
            if (lane == 0) minsh[wv][b] = m;
        }
        __syncthreads();  // minsh visible; rowbuf reads complete
        if (t < BATCH) {
            float m = fminf(fminf(minsh[0][t], minsh[1][t]), fminf(minsh[2][t], minsh[3][t]));
            t1sum += pb[t] * m;
        }
    }
    #pragma unroll
    for (int k = 0; k < 8; k++) atomicAdd(&wsf[WS_S + t + 256 * k], acc[k]);
    if (t < BATCH) atomicAdd(&wsf[WS_T1 + t], t1sum);
}

__global__ __launch_bounds__(256) void whd_k4_out(const float* __restrict__ wsf,
                                                  float* __restrict__ out) {
    __shared__ float red[256];
    int t = threadIdx.x;
    // term2 = mean_b mean_g N/S = global mean over 2048 of N/S (uniform weights)
    float s = 0.f;
    for (int i = t; i < BG; i += 256) s += (float)N_POS / wsf[WS_S + i];
    red[t] = s; __syncthreads();
    for (int st = 128; st; st >>= 1) { if (t < st) red[t] += red[t + st]; __syncthreads(); }
    if (t == 0) {
        float term2 = red[0] / (float)BG;
        float term1 = 0.f;
        for (int b = 0; b < BATCH; b++)
            term1 += wsf[WS_T1 + b] / (wsf[WS_SC + 3 + b] + EPSV);
        term1 *= (1.0f / BATCH);
        out[0] = term1 + term2;
    }
}

extern "C" void kernel_launch(void* const* d_in, const int* in_sizes, int n_in,
                              void* d_out, int out_size, void* d_ws, size_t ws_size,
                              hipStream_t stream) {
    const float* prob = (const float*)d_in[0];       // (4, 8192) fp32
    const int* gt = (const int*)d_in[1];             // (4, 512) int32
    const float* dis = (const float*)d_in[2];        // (8192, 8192) fp32
    float* out = (float*)d_out;
    float* wsf = (float*)d_ws;

    whd_k1_max<<<K1_BLOCKS, 256, 0, stream>>>((const float4*)dis, wsf + WS_PART_MAX);
    whd_k2_scalars<<<1, 1024, 0, stream>>>(prob, wsf);
    whd_k3_main<<<N_POS / ROWS_PER_BLOCK, 256, 0, stream>>>(dis, prob, gt, wsf);
    whd_k4_out<<<1, 256, 0, stream>>>(wsf, out);
}